// Round 15
// baseline (511.097 us; speedup 1.0000x reference)
//
#include <hip/hip_runtime.h>

#define N_   128
#define C_   12
#define L_   2048
#define H_   32
#define K_   8
#define CP_  6
#define KW_  9
#define FEAT_ 8192   // D*DIV*2*H*K

// s_buf: [0..3071] padded conv input, then reused as 16x16x17 reduce matrix
#define SBUF_ 4352

template<int DIL, bool GUARD>
__device__ __forceinline__ void conv_phase(const float* __restrict__ s,
                                           const float* __restrict__ wr,
                                           float* __restrict__ cx,
                                           int* __restrict__ cn,
                                           const int tid)
{
    if constexpr (DIL == 1) {
        // sliding 12-float window, 2 groups of 4 consecutive positions
        #pragma unroll
        for (int g = 0; g < 2; ++g) {
            const int t = g * 1024 + 4 * tid;
            float win[12];
            #pragma unroll
            for (int q = 0; q < 3; ++q) {
                const float4 v = *(const float4*)(s + t + 4 * q);  // ds_read_b128
                win[4*q+0] = v.x; win[4*q+1] = v.y;
                win[4*q+2] = v.z; win[4*q+3] = v.w;
            }
            #pragma unroll
            for (int p = 0; p < 4; ++p) {
                if (GUARD && g == 1 && p == 3 && tid == 255) continue;  // pos 2047
                float a0 = 0.f, a1 = 0.f, a2 = 0.f, a3 = 0.f,
                      a4 = 0.f, a5 = 0.f, a6 = 0.f, a7 = 0.f;
                #pragma unroll
                for (int w = 0; w < KW_; ++w) {
                    const float v = win[p + w];
                    a0 = fmaf(v, wr[0 * KW_ + w], a0);
                    a1 = fmaf(v, wr[1 * KW_ + w], a1);
                    a2 = fmaf(v, wr[2 * KW_ + w], a2);
                    a3 = fmaf(v, wr[3 * KW_ + w], a3);
                    a4 = fmaf(v, wr[4 * KW_ + w], a4);
                    a5 = fmaf(v, wr[5 * KW_ + w], a5);
                    a6 = fmaf(v, wr[6 * KW_ + w], a6);
                    a7 = fmaf(v, wr[7 * KW_ + w], a7);
                }
                const float mxa = fmaxf(fmaxf(a0, a1), a2);
                const float mxb = fmaxf(fmaxf(a3, a4), a5);
                const float mxc = fmaxf(fmaxf(a6, a7), mxa);
                const float mx  = fmaxf(mxb, mxc);
                const float mna = fminf(fminf(a0, a1), a2);
                const float mnb = fminf(fminf(a3, a4), a5);
                const float mnc = fminf(fminf(a6, a7), mna);
                const float mn  = fminf(mnb, mnc);
                cx[0] += (a0 == mx) ? a0 : 0.f;  cn[0] += (a0 == mn);
                cx[1] += (a1 == mx) ? a1 : 0.f;  cn[1] += (a1 == mn);
                cx[2] += (a2 == mx) ? a2 : 0.f;  cn[2] += (a2 == mn);
                cx[3] += (a3 == mx) ? a3 : 0.f;  cn[3] += (a3 == mn);
                cx[4] += (a4 == mx) ? a4 : 0.f;  cn[4] += (a4 == mn);
                cx[5] += (a5 == mx) ? a5 : 0.f;  cn[5] += (a5 == mn);
                cx[6] += (a6 == mx) ? a6 : 0.f;  cn[6] += (a6 == mn);
                cx[7] += (a7 == mx) ? a7 : 0.f;  cn[7] += (a7 == mn);
            }
        }
    } else {
        // 4 subgroups x 2 consecutive positions; 9 float2 window (18 regs)
        #pragma unroll
        for (int g = 0; g < 4; ++g) {
            const int t = g * 512 + 2 * tid;
            float2 wv[9];
            #pragma unroll
            for (int w = 0; w < KW_; ++w)
                wv[w] = *(const float2*)(s + t + w * DIL);   // ds_read_b64
            #pragma unroll
            for (int p = 0; p < 2; ++p) {
                if (GUARD && g == 3 && p == 1 && tid == 255) continue;  // pos 2047
                float a0 = 0.f, a1 = 0.f, a2 = 0.f, a3 = 0.f,
                      a4 = 0.f, a5 = 0.f, a6 = 0.f, a7 = 0.f;
                #pragma unroll
                for (int w = 0; w < KW_; ++w) {
                    const float v = p ? wv[w].y : wv[w].x;
                    a0 = fmaf(v, wr[0 * KW_ + w], a0);
                    a1 = fmaf(v, wr[1 * KW_ + w], a1);
                    a2 = fmaf(v, wr[2 * KW_ + w], a2);
                    a3 = fmaf(v, wr[3 * KW_ + w], a3);
                    a4 = fmaf(v, wr[4 * KW_ + w], a4);
                    a5 = fmaf(v, wr[5 * KW_ + w], a5);
                    a6 = fmaf(v, wr[6 * KW_ + w], a6);
                    a7 = fmaf(v, wr[7 * KW_ + w], a7);
                }
                const float mxa = fmaxf(fmaxf(a0, a1), a2);
                const float mxb = fmaxf(fmaxf(a3, a4), a5);
                const float mxc = fmaxf(fmaxf(a6, a7), mxa);
                const float mx  = fmaxf(mxb, mxc);
                const float mna = fminf(fminf(a0, a1), a2);
                const float mnb = fminf(fminf(a3, a4), a5);
                const float mnc = fminf(fminf(a6, a7), mna);
                const float mn  = fminf(mnb, mnc);
                cx[0] += (a0 == mx) ? a0 : 0.f;  cn[0] += (a0 == mn);
                cx[1] += (a1 == mx) ? a1 : 0.f;  cn[1] += (a1 == mn);
                cx[2] += (a2 == mx) ? a2 : 0.f;  cn[2] += (a2 == mn);
                cx[3] += (a3 == mx) ? a3 : 0.f;  cn[3] += (a3 == mn);
                cx[4] += (a4 == mx) ? a4 : 0.f;  cn[4] += (a4 == mn);
                cx[5] += (a5 == mx) ? a5 : 0.f;  cn[5] += (a5 == mn);
                cx[6] += (a6 == mx) ? a6 : 0.f;  cn[6] += (a6 == mn);
                cx[7] += (a7 == mx) ? a7 : 0.f;  cn[7] += (a7 == mn);
            }
        }
    }
}

// min 5 waves/EU -> VGPR cap ~51 -> 5 waves/SIMD (was 4 at 64 VGPR).
// R8 lesson: forcing 8 waves (cap 32) spills catastrophically; 5 is the
// next gentle occupancy boundary. Spill tripwire: FETCH_SIZE > ~20 MB.
__global__ __launch_bounds__(256, 5) void hydra_kernel(
    const float* __restrict__ X,   // [N, C, L]
    const float* __restrict__ W,   // [D, DIV, K*H, 1, KW]
    const int*   __restrict__ I,   // [D, DIV, H, CP]
    float* __restrict__ out)       // [N, FEAT]
{
    __shared__ __align__(16) float s_buf[SBUF_];

    const int tid   = threadIdx.x;
    // ---- XCD-aware swizzle (T1): XCD k = blockIdx%8 owns n in [16k, 16k+16) ----
    const int b_raw = blockIdx.x;
    const int xcd   = b_raw & 7;
    const int sub   = b_raw >> 3;          // 0..8191
    const int n     = xcd * 16 + (sub >> 9);
    const int rem   = sub & 511;
    const int comb  = rem >> 5;            // di*2 + df
    const int h     = rem & 31;

    const int df   = comb & 1;
    const int di   = comb >> 1;
    const int d    = 1 << di;
    const int pad  = 4 * d;

    // ---- zero init, stride-1 (conflict-free) ----
    #pragma unroll
    for (int i = 0; i < 12; ++i) s_buf[tid + i * 256] = 0.0f;

    // block-uniform channel indices (scalarized)
    const int* Ib = I + (comb * H_ + h) * CP_;
    const int c0 = Ib[0], c1 = Ib[1], c2 = Ib[2],
              c3 = Ib[3], c4 = Ib[4], c5 = Ib[5];
    const float* Xn = X + (size_t)n * (C_ * L_);
    const float* xp0 = Xn + c0 * L_;
    const float* xp1 = Xn + c1 * L_;
    const float* xp2 = Xn + c2 * L_;
    const float* xp3 = Xn + c3 * L_;
    const float* xp4 = Xn + c4 * L_;
    const float* xp5 = Xn + c5 * L_;

    // block-uniform weights -> SGPRs
    const float* Wb = W + (size_t)(comb * (K_ * H_) + h * K_) * KW_;
    float wr[K_ * KW_];
    #pragma unroll
    for (int q = 0; q < K_ * KW_; ++q) wr[q] = Wb[q];

    __syncthreads();   // zeros visible

    // ---- staging: two 3-channel bursts (24 in-flight loads each, VGPR-lean) ----
    {
        float ssum[8];
        {
            float l0[8], l1[8], l2[8];
            #pragma unroll
            for (int i = 0; i < 8; ++i) {
                const int t = tid + i * 256;
                l0[i] = xp0[t]; l1[i] = xp1[t]; l2[i] = xp2[t];
            }
            #pragma unroll
            for (int i = 0; i < 8; ++i)
                ssum[i] = (l0[i] + l1[i]) + l2[i];
        }
        {
            float l0[8], l1[8], l2[8];
            #pragma unroll
            for (int i = 0; i < 8; ++i) {
                const int t = tid + i * 256;
                l0[i] = xp3[t]; l1[i] = xp4[t]; l2[i] = xp5[t];
            }
            #pragma unroll
            for (int i = 0; i < 8; ++i) {
                const int t = tid + i * 256;
                s_buf[pad + t] = ssum[i] + ((l0[i] + l1[i]) + l2[i]);
            }
        }
    }
    __syncthreads();

    // ---- df=1: in-place diff pass, d[t] = S[t+1]-S[t] ----
    if (df == 1) {
        float dv[8];
        #pragma unroll
        for (int i = 0; i < 8; ++i) {
            const int t = tid + i * 256;
            dv[i] = s_buf[pad + t + 1] - s_buf[pad + t];   // pad+2048 is zero region
        }
        __syncthreads();
        #pragma unroll
        for (int i = 0; i < 8; ++i) {
            const int t = tid + i * 256;
            s_buf[pad + t] = (i == 7 && tid == 255) ? 0.0f : dv[i];  // t=2047 not in Lsrc
        }
        __syncthreads();
    }

    // ---- conv + equality-scatter (templated dilation) ----
    float cx[K_] = {0.f, 0.f, 0.f, 0.f, 0.f, 0.f, 0.f, 0.f};
    int   cn[K_] = {0, 0, 0, 0, 0, 0, 0, 0};

    switch (comb) {
        case  0: conv_phase<  1, false>(s_buf, wr, cx, cn, tid); break;
        case  1: conv_phase<  1, true >(s_buf, wr, cx, cn, tid); break;
        case  2: conv_phase<  2, false>(s_buf, wr, cx, cn, tid); break;
        case  3: conv_phase<  2, true >(s_buf, wr, cx, cn, tid); break;
        case  4: conv_phase<  4, false>(s_buf, wr, cx, cn, tid); break;
        case  5: conv_phase<  4, true >(s_buf, wr, cx, cn, tid); break;
        case  6: conv_phase<  8, false>(s_buf, wr, cx, cn, tid); break;
        case  7: conv_phase<  8, true >(s_buf, wr, cx, cn, tid); break;
        case  8: conv_phase< 16, false>(s_buf, wr, cx, cn, tid); break;
        case  9: conv_phase< 16, true >(s_buf, wr, cx, cn, tid); break;
        case 10: conv_phase< 32, false>(s_buf, wr, cx, cn, tid); break;
        case 11: conv_phase< 32, true >(s_buf, wr, cx, cn, tid); break;
        case 12: conv_phase< 64, false>(s_buf, wr, cx, cn, tid); break;
        case 13: conv_phase< 64, true >(s_buf, wr, cx, cn, tid); break;
        case 14: conv_phase<128, false>(s_buf, wr, cx, cn, tid); break;
        default: conv_phase<128, true >(s_buf, wr, cx, cn, tid); break;
    }

    __syncthreads();   // conv done reading s_buf

    // ---- conflict-free reduce matrix ----
    // accumulator r of source thread s lives at s_buf[(r*16 + (s>>4))*17 + (s&15)]
    {
        const int wc = tid >> 4;   // 0..15
        const int wu = tid & 15;   // 0..15
        #pragma unroll
        for (int k = 0; k < K_; ++k) {
            s_buf[((k     ) * 16 + wc) * 17 + wu] = cx[k];
            s_buf[((k + 8 ) * 16 + wc) * 17 + wu] = (float)cn[k];
        }
    }
    __syncthreads();

    {
        const int r = tid >> 4;    // accumulator id 0..15
        const int c = tid & 15;    // chunk id 0..15
        const int base = (r * 16 + c) * 17;
        float p = 0.f;
        #pragma unroll
        for (int u = 0; u < 16; ++u)
            p += s_buf[base + u];
        #pragma unroll
        for (int off = 1; off < 16; off <<= 1)
            p += __shfl_xor(p, off, 64);
        if (c == 0) {
            const int s = r >> 3;      // 0 = cmax, 1 = cmin
            const int k = r & 7;
            out[(size_t)n * FEAT_ + (comb * 2 + s) * (H_ * K_) + h * K_ + k] = p;
        }
    }
}

extern "C" void kernel_launch(void* const* d_in, const int* in_sizes, int n_in,
                              void* d_out, int out_size, void* d_ws, size_t ws_size,
                              hipStream_t stream) {
    const float* X = (const float*)d_in[0];
    const float* W = (const float*)d_in[1];
    const int*   I = (const int*)d_in[2];
    float* out = (float*)d_out;

    const int blocks = N_ * 16 * H_;   // 65536: (n, di, df, h)
    hipLaunchKernelGGL(hydra_kernel, dim3(blocks), dim3(256), 0, stream,
                       X, W, I, out);
}